// Round 14
// baseline (323.688 us; speedup 1.0000x reference)
//
#include <hip/hip_runtime.h>

// STU layer: out[b,t,e] = sum_{k,d} phi[t,k] * C[b,t,k,d] * W[k,e,d],
//            C = cumsum_t(phi[t,k] * x[b,t,d])
// Fused: out = A @ WT^T (M=16384, Kdim=4096, N=256); the A-tile
// (A[bt, d*16+k] = phi[t,k]*C[b,t,k,d]) is built on the fly in LDS from
// 16-step cumsum chains seeded by chunk-prefix states U.
// R13: R2's proven fused kernel, restructured for MAX RESIDENCY:
// single-buffered A (8KB) + B (32KB) = 40KB LDS, ks-split=4, grid (256,4)
// = 4 blocks/CU = 32 waves/CU. 2-barrier schedule (build strictly after
// MFMA) makes single-buffering legal; cross-block phase stagger hides the
// per-step stalls (m97 mechanism).
// B=4, T=4096, D=256, K=16, chunk CH=16 (256 chunks/batch).

typedef __bf16 bf16x8 __attribute__((ext_vector_type(8)));
typedef float  f32x4  __attribute__((ext_vector_type(4)));
typedef unsigned short u16;

__device__ static inline u16 f2bf(float f) {          // RNE f32->bf16
    unsigned int u = __float_as_uint(f);
    u = (u + 0x7fffu + ((u >> 16) & 1u)) >> 16;
    return (u16)u;
}

__device__ static inline void gload16(const void* g, void* l) {
    __builtin_amdgcn_global_load_lds((const __attribute__((address_space(1))) void*)g,
                                     (__attribute__((address_space(3))) void*)l, 16, 0, 0);
}

// ---------------- k0: WT[e][d*16+k] = bf16(W[k][e][d]) ----------------
__global__ __launch_bounds__(256) void k0_wt(const float* __restrict__ W, u16* __restrict__ WT) {
    const int e = blockIdx.x, d = threadIdx.x;
    union { u16 u[16]; uint4 v[2]; } ob;
#pragma unroll
    for (int k = 0; k < 16; ++k)
        ob.u[k] = f2bf(W[((size_t)k * 256 + e) * 256 + d]);
    uint4* dst = (uint4*)(WT + (size_t)e * 4096 + d * 16);
    dst[0] = ob.v[0]; dst[1] = ob.v[1];
}

// ---------------- k1: chunk sums U[b,c,d,k] = sum_{s in 16-chunk} phi*x ----------------
__global__ __launch_bounds__(256) void k1_sums(const float* __restrict__ x,
                                               const float* __restrict__ phi,
                                               float* __restrict__ U) {
    __shared__ float phis[256];
    const int tid = threadIdx.x;
    const int b = blockIdx.x, c = blockIdx.y;
    const int t0 = c * 16;
    phis[tid] = phi[t0 * 16 + tid];
    __syncthreads();
    float acc[16];
#pragma unroll
    for (int k = 0; k < 16; ++k) acc[k] = 0.f;
    for (int s = 0; s < 16; ++s) {
        const float xv = x[(size_t)((b << 12) + t0 + s) * 256 + tid];
        union { float f[16]; float4 v[4]; } pv;
#pragma unroll
        for (int j = 0; j < 4; ++j) pv.v[j] = *(const float4*)&phis[s * 16 + j * 4];
#pragma unroll
        for (int k = 0; k < 16; ++k) acc[k] = fmaf(pv.f[k], xv, acc[k]);
    }
    float4* Up = (float4*)(U + ((size_t)((b * 256 + c) * 256 + tid)) * 16);
    union { float f[16]; float4 v[4]; } ov;
#pragma unroll
    for (int k = 0; k < 16; ++k) ov.f[k] = acc[k];
#pragma unroll
    for (int j = 0; j < 4; ++j) Up[j] = ov.v[j];
}

// ---------------- k2: exclusive scan of U over c (in place), coalesced ----------------
__global__ __launch_bounds__(256) void k2_scan(float* __restrict__ U) {
    const int b  = blockIdx.x;                     // grid (4,64)
    const int dl = threadIdx.x & 63;
    const int dk = blockIdx.y * 64 + dl;
    const int q  = threadIdx.x >> 6;               // c-quarter 0..3
    float* base = U + (size_t)b * 1048576 + (size_t)(q * 64) * 4096 + dk;
    float s = 0.f;
#pragma unroll 8
    for (int j = 0; j < 64; ++j) s += base[(size_t)j * 4096];
    __shared__ float qs[4][64];
    qs[q][dl] = s;
    __syncthreads();
    float pre = 0.f;
#pragma unroll
    for (int i = 0; i < 4; ++i) pre += (i < q) ? qs[i][dl] : 0.f;
    float run = pre;
#pragma unroll 8
    for (int j = 0; j < 64; ++j) {
        const float v = base[(size_t)j * 4096];
        base[(size_t)j * 4096] = run;
        run += v;
    }
}

// ---------------- k4: fused A-build + GEMM, ks-split=4, 4 blocks/CU ----------------
// BM=64, BN=256, BK=64, 16 K-steps. 512 thr = 8 waves (2M x 4N, 32x64 wave
// tiles). Waves 0-3: build A-tile (256 cumsum chains, one per lane, inline x
// loads). Waves 4-7: stage B via global_load_lds. Single-buffered A+B
// (40KB LDS -> 4 blocks/CU = 32 waves/CU): build phase strictly after the
// MFMA phase (2 barriers/step), residency hides the serialization.
__global__ __launch_bounds__(512, 8) void k4_fused(const float* __restrict__ x,
                                                   const float* __restrict__ phi,
                                                   const float* __restrict__ U,
                                                   const u16* __restrict__ BT,
                                                   float* __restrict__ C) {
    __shared__ __align__(16) char smem[40960];   // A 8KB @0, B 32KB @8192
    const int tid = threadIdx.x;
    const int m0 = blockIdx.x * 64;              // global row base (bt)
    const int ks = blockIdx.y;                   // kdim quarter 0..3
    const int b  = m0 >> 12, t0 = m0 & 4095, c0 = t0 >> 4;
    const int w = tid >> 6, l = tid & 63;
    const int wm = (w >> 2) * 32, wn = (w & 3) * 64;
    const int lg = l >> 4, lr = l & 15;
    f32x4 acc[2][4] = {};

    // chain-lane constants (waves 0-3): chain = (chunk=w, d-local=lg, k=lr)
    float p[16];
    if (w < 4) {
#pragma unroll
        for (int s = 0; s < 16; ++s) p[s] = phi[(t0 + w * 16 + s) * 16 + lr];
    }
    const char* Bb = (const char*)BT;
    const int tl = tid & 255;
    const int colb = (lg * 16 + lr) * 2;         // A-tile column byte for chain lane

    auto stageB = [&](int kt) {                  // waves 4-7: 8 x gload16 each
        const int kofs = ks * 2048 + kt * 128;   // byte offset in 8192B WT row
#pragma unroll
        for (int c = 0; c < 8; ++c) {
            const int row = c * 32 + (tl >> 3);
            gload16(Bb + (size_t)row * 8192 + kofs + (((tl & 7) * 16) ^ ((row & 7) << 4)),
                    smem + 8192 + c * 4096 + tl * 16);
        }
    };
    auto chains = [&](int kt) {                  // waves 0-3: one 16-step chain
        const int d = ks * 64 + kt * 4 + lg;
        float run = U[(((size_t)(b * 256 + c0 + w)) * 256 + d) * 16 + lr];
        char* Ab = smem + w * 2048;              // chunk w -> rows w*16..w*16+15
#pragma unroll
        for (int s = 0; s < 16; ++s) {
            const float xv = x[(size_t)(m0 + w * 16 + s) * 256 + d];
            run = fmaf(p[s], xv, run);
            *(u16*)(Ab + s * 128 + (colb ^ ((s & 7) << 4))) = f2bf(p[s] * run);
        }
    };

    // prologue: fill buffers for step 0
    if (w >= 4) stageB(0); else chains(0);
    __syncthreads();

    for (int kt = 0; kt < 16; ++kt) {
        const char* Abase = smem;
        const char* Bbase = smem + 8192;
#pragma unroll
        for (int kk = 0; kk < 2; ++kk) {
            const int kb = kk * 64 + lg * 16;
            bf16x8 af[2], bfv[4];
#pragma unroll
            for (int mi = 0; mi < 2; ++mi) {
                const int r = wm + mi * 16 + lr;
                af[mi] = *(const bf16x8*)(Abase + r * 128 + (kb ^ ((r & 7) << 4)));
            }
#pragma unroll
            for (int ni = 0; ni < 4; ++ni) {
                const int n = wn + ni * 16 + lr;
                bfv[ni] = *(const bf16x8*)(Bbase + n * 128 + (kb ^ ((n & 7) << 4)));
            }
#pragma unroll
            for (int mi = 0; mi < 2; ++mi)
#pragma unroll
                for (int ni = 0; ni < 4; ++ni)
                    acc[mi][ni] = __builtin_amdgcn_mfma_f32_16x16x32_bf16(af[mi], bfv[ni], acc[mi][ni], 0, 0, 0);
        }
        __syncthreads();                          // done reading A,B
        if (kt < 15) {                            // rebuild same buffers for kt+1
            if (w >= 4) stageB(kt + 1);
            else        chains(kt + 1);
            __syncthreads();                      // drains vmcnt (B) + lgkm (A)
        }
    }

    // epilogue: four contributions per out element (ks=0..3), commutative f32 adds
#pragma unroll
    for (int mi = 0; mi < 2; ++mi)
#pragma unroll
        for (int ni = 0; ni < 4; ++ni)
#pragma unroll
            for (int r = 0; r < 4; ++r) {
                const int row = m0 + wm + mi * 16 + lg * 4 + r;
                const int col = wn + ni * 16 + lr;
                unsafeAtomicAdd(&C[(size_t)row * 256 + col], acc[mi][ni][r]);
            }
}

extern "C" void kernel_launch(void* const* d_in, const int* in_sizes, int n_in,
                              void* d_out, int out_size, void* d_ws, size_t ws_size,
                              hipStream_t stream) {
    const float* x   = (const float*)d_in[0];   // (4,4096,256)
    const float* W   = (const float*)d_in[1];   // (16,256,256)
    const float* phi = (const float*)d_in[2];   // (4096,16)
    float* out = (float*)d_out;                 // (4,4096,256) f32

    char* ws = (char*)d_ws;
    u16*   WT = (u16*)ws;                       // 2 MB
    float* U  = (float*)(ws + (2u << 20));      // 16 MB

    k0_wt  <<<256, 256, 0, stream>>>(W, WT);
    k1_sums<<<dim3(4, 256), 256, 0, stream>>>(x, phi, U);
    k2_scan<<<dim3(4, 64), 256, 0, stream>>>(U);
    hipMemsetAsync(d_out, 0, (size_t)out_size * sizeof(float), stream);
    k4_fused<<<dim3(256, 4), 512, 0, stream>>>(x, phi, U, WT, out);
}

// Round 15
// 123.152 us; speedup vs baseline: 2.6284x; 2.6284x over previous
//
#include <hip/hip_runtime.h>

// STU layer: out[b,t,e] = sum_{k,d} phi[t,k] * C[b,t,k,d] * W[k,e,d],
//            C = cumsum_t(phi[t,k] * x[b,t,d])
// Fused: out = A @ WT^T (M=16384, Kdim=4096, N=256); A-tile built in LDS from
// kf-pair cumsum chains seeded by chunk-prefix states U.
// R14: m97-replica geometry -- 256-thread blocks (4 waves of 64x64),
// BM=128 x BN=128, BK=64, ks-split=4, single-buffered A+B+phi = 40KB LDS,
// 2-barrier K-step, launch_bounds(256,3) (170 VGPR headroom, NO spill).
// grid (256,4) = 1024 blocks -> 3-4 blocks/CU residency.
// B=4, T=4096, D=256, K=16, chunk CH=16.

typedef __bf16 bf16x8 __attribute__((ext_vector_type(8)));
typedef float  f32x4  __attribute__((ext_vector_type(4)));
typedef unsigned short u16;
typedef unsigned int   u32;

__device__ static inline u16 f2bf(float f) {          // RNE f32->bf16
    unsigned int u = __float_as_uint(f);
    u = (u + 0x7fffu + ((u >> 16) & 1u)) >> 16;
    return (u16)u;
}

__device__ static inline void gload16(const void* g, void* l) {
    __builtin_amdgcn_global_load_lds((const __attribute__((address_space(1))) void*)g,
                                     (__attribute__((address_space(3))) void*)l, 16, 0, 0);
}

// ---------------- k0: WT[e][d*16+k] = bf16(W[k][e][d]) ----------------
__global__ __launch_bounds__(256) void k0_wt(const float* __restrict__ W, u16* __restrict__ WT) {
    const int e = blockIdx.x, d = threadIdx.x;
    union { u16 u[16]; uint4 v[2]; } ob;
#pragma unroll
    for (int k = 0; k < 16; ++k)
        ob.u[k] = f2bf(W[((size_t)k * 256 + e) * 256 + d]);
    uint4* dst = (uint4*)(WT + (size_t)e * 4096 + d * 16);
    dst[0] = ob.v[0]; dst[1] = ob.v[1];
}

// ---------------- k1: chunk sums U[b,c,d,k] = sum_{s in 16-chunk} phi*x ----------------
__global__ __launch_bounds__(256) void k1_sums(const float* __restrict__ x,
                                               const float* __restrict__ phi,
                                               float* __restrict__ U) {
    __shared__ float phis[256];
    const int tid = threadIdx.x;
    const int b = blockIdx.x, c = blockIdx.y;
    const int t0 = c * 16;
    phis[tid] = phi[t0 * 16 + tid];
    __syncthreads();
    float acc[16];
#pragma unroll
    for (int k = 0; k < 16; ++k) acc[k] = 0.f;
    for (int s = 0; s < 16; ++s) {
        const float xv = x[(size_t)((b << 12) + t0 + s) * 256 + tid];
        union { float f[16]; float4 v[4]; } pv;
#pragma unroll
        for (int j = 0; j < 4; ++j) pv.v[j] = *(const float4*)&phis[s * 16 + j * 4];
#pragma unroll
        for (int k = 0; k < 16; ++k) acc[k] = fmaf(pv.f[k], xv, acc[k]);
    }
    float4* Up = (float4*)(U + ((size_t)((b * 256 + c) * 256 + tid)) * 16);
    union { float f[16]; float4 v[4]; } ov;
#pragma unroll
    for (int k = 0; k < 16; ++k) ov.f[k] = acc[k];
#pragma unroll
    for (int j = 0; j < 4; ++j) Up[j] = ov.v[j];
}

// ---------------- k2: exclusive scan of U over c (in place), coalesced ----------------
__global__ __launch_bounds__(256) void k2_scan(float* __restrict__ U) {
    const int b  = blockIdx.x;                     // grid (4,64)
    const int dl = threadIdx.x & 63;
    const int dk = blockIdx.y * 64 + dl;
    const int q  = threadIdx.x >> 6;               // c-quarter 0..3
    float* base = U + (size_t)b * 1048576 + (size_t)(q * 64) * 4096 + dk;
    float s = 0.f;
#pragma unroll 8
    for (int j = 0; j < 64; ++j) s += base[(size_t)j * 4096];
    __shared__ float qs[4][64];
    qs[q][dl] = s;
    __syncthreads();
    float pre = 0.f;
#pragma unroll
    for (int i = 0; i < 4; ++i) pre += (i < q) ? qs[i][dl] : 0.f;
    float run = pre;
#pragma unroll 8
    for (int j = 0; j < 64; ++j) {
        const float v = base[(size_t)j * 4096];
        base[(size_t)j * 4096] = run;
        run += v;
    }
}

// ---------------- k4: fused A-build + GEMM, m97 geometry, ks-split=4 ----------------
// BM=128, BN=128, BK=64, 16 K-steps. 256 thr = 4 waves, each 64x64
// (acc[4][4]). All threads: 2 kf-pair chains (phi from LDS) + 4 B-stage
// gload16 + 32 MFMA/step. Single-buffered, 2 barriers/step.
// LDS 40KB: A[16384]@0, B[16384]@16384, phis[8192]@32768.
__global__ __launch_bounds__(256, 3) void k4_fused(const float* __restrict__ x,
                                                   const float* __restrict__ phi,
                                                   const float* __restrict__ U,
                                                   const u16* __restrict__ BT,
                                                   float* __restrict__ C) {
    __shared__ __align__(16) char smem[40960];
    const int tid = threadIdx.x;
    const int mb = blockIdx.x >> 1, nb = blockIdx.x & 1;
    const int ks = blockIdx.y;                   // kdim quarter 0..3
    const int m0 = mb * 128, n0 = nb * 128;
    const int b  = m0 >> 12, t0 = m0 & 4095, c0 = t0 >> 4;
    const int w = tid >> 6, l = tid & 63;
    const int wm = (w >> 1) * 64, wn = (w & 1) * 64;
    const int lg = l >> 4, lr = l & 15;
    f32x4 acc[4][4] = {};

    // chain mapping: tid = ch*32 + dl*8 + kp  (2 chains: k = 2kp, 2kp+1)
    const int kp = tid & 7, dl = (tid >> 3) & 3, ch = tid >> 5;   // ch 0..7
    const int colb = dl * 32 + kp * 4;
    const char* pb = smem + 32768 + (ch * 16) * 64 + kp * 8;

    // B staging: 4 gload16/thread; row = c*32 + tr
    const int tr = tid >> 3;
    const char* bsrc = (const char*)BT + (size_t)(n0 + tr) * 8192 + ks * 2048
                     + (((tid & 7) * 16) ^ ((tr & 7) << 4));

    auto stageB = [&](int kt) {
        const char* src = bsrc + (size_t)kt * 128;
        char* dst = smem + 16384 + tid * 16;
#pragma unroll
        for (int c = 0; c < 4; ++c)
            gload16(src + (size_t)c * 262144, dst + c * 4096);
    };
    auto chains = [&](int kt) {
        const int d = ks * 64 + kt * 4 + dl;
        const float2 us = *(const float2*)&U[((size_t)((b * 256 + c0 + ch) * 256 + d)) * 16 + kp * 2];
        const float* xp = x + (size_t)(m0 + ch * 16) * 256 + d;
        float r0 = us.x, r1 = us.y;
        char* Ab = smem + ch * 2048;
#pragma unroll
        for (int s = 0; s < 16; ++s) {
            const float2 p = *(const float2*)(pb + s * 64);
            const float xv = xp[(size_t)s * 256];
            r0 = fmaf(p.x, xv, r0);
            r1 = fmaf(p.y, xv, r1);
            const float v0 = p.x * r0, v1 = p.y * r1;
            u32 pk;
            asm("v_cvt_pk_bf16_f32 %0, %1, %2" : "=v"(pk) : "v"(v0), "v"(v1));
            *(u32*)(Ab + s * 128 + (colb ^ ((s & 7) << 4))) = pk;
        }
    };
    auto mfma_phase = [&]() {
        const char* Abase = smem;
        const char* Bbase = smem + 16384;
#pragma unroll
        for (int kk = 0; kk < 2; ++kk) {
            const int kb = kk * 64 + lg * 16;
            bf16x8 af[4], bfv[4];
#pragma unroll
            for (int mi = 0; mi < 4; ++mi) {
                const int r = wm + mi * 16 + lr;
                af[mi] = *(const bf16x8*)(Abase + r * 128 + (kb ^ ((r & 7) << 4)));
            }
#pragma unroll
            for (int ni = 0; ni < 4; ++ni) {
                const int n = wn + ni * 16 + lr;
                bfv[ni] = *(const bf16x8*)(Bbase + n * 128 + (kb ^ ((n & 7) << 4)));
            }
#pragma unroll
            for (int mi = 0; mi < 4; ++mi)
#pragma unroll
                for (int ni = 0; ni < 4; ++ni)
                    acc[mi][ni] = __builtin_amdgcn_mfma_f32_16x16x32_bf16(
                        af[mi], bfv[ni], acc[mi][ni], 0, 0, 0);
        }
    };

    // prologue: phi tile -> LDS; B(0) in flight; barrier; A(0) chains; barrier
    {
        const float4* psrc = (const float4*)(phi + (size_t)t0 * 16) + tid * 2;
        float4* pdst = (float4*)(smem + 32768) + tid * 2;
        pdst[0] = psrc[0]; pdst[1] = psrc[1];
    }
    stageB(0);
    __syncthreads();                 // phis visible, B(0) landed
    chains(0);
    __syncthreads();                 // A(0) visible

    for (int kt = 0; kt < 16; ++kt) {
        __builtin_amdgcn_s_setprio(1);
        mfma_phase();
        __builtin_amdgcn_s_setprio(0);
        __syncthreads();             // done reading A,B
        if (kt < 15) {
            stageB(kt + 1);
            chains(kt + 1);
            __syncthreads();         // drains vm (B) + lgkm (A writes)
        }
    }

    // epilogue: four contributions per element (ks=0..3), commutative f32 adds
#pragma unroll
    for (int mi = 0; mi < 4; ++mi)
#pragma unroll
        for (int ni = 0; ni < 4; ++ni)
#pragma unroll
            for (int r = 0; r < 4; ++r) {
                const int row = m0 + wm + mi * 16 + lg * 4 + r;
                const int col = n0 + wn + ni * 16 + lr;
                unsafeAtomicAdd(&C[(size_t)row * 256 + col], acc[mi][ni][r]);
            }
}

extern "C" void kernel_launch(void* const* d_in, const int* in_sizes, int n_in,
                              void* d_out, int out_size, void* d_ws, size_t ws_size,
                              hipStream_t stream) {
    const float* x   = (const float*)d_in[0];   // (4,4096,256)
    const float* W   = (const float*)d_in[1];   // (16,256,256)
    const float* phi = (const float*)d_in[2];   // (4096,16)
    float* out = (float*)d_out;                 // (4,4096,256) f32

    char* ws = (char*)d_ws;
    u16*   WT = (u16*)ws;                       // 2 MB
    float* U  = (float*)(ws + (2u << 20));      // 16 MB

    k0_wt  <<<256, 256, 0, stream>>>(W, WT);
    k1_sums<<<dim3(4, 256), 256, 0, stream>>>(x, phi, U);
    k2_scan<<<dim3(4, 64), 256, 0, stream>>>(U);
    hipMemsetAsync(d_out, 0, (size_t)out_size * sizeof(float), stream);
    k4_fused<<<dim3(256, 4), 256, 0, stream>>>(x, phi, U, WT, out);
}

// Round 16
// 120.145 us; speedup vs baseline: 2.6941x; 1.0250x over previous
//
#include <hip/hip_runtime.h>

// STU layer: out[b,t,e] = sum_{k,d} phi[t,k] * C[b,t,k,d] * W[k,e,d],
//            C = cumsum_t(phi[t,k] * x[b,t,d])
// Fused: out = A @ WT^T (M=16384, Kdim=4096, N=256); A-tile built in LDS from
// kf-pair cumsum chains seeded by chunk-prefix states U.
// R15 = R14 (m97 geometry: 256-thr blocks, BM=128 x BN=128, BK=64, ks=4,
// 40KB LDS, 4 blocks/CU) with ONE change: chains read x from the
// PRE-TRANSPOSED xT[b][d][t] (emitted by k1) -- 64B contiguous per lane
// instead of 16 scattered stride-1024B dwords (R14's 143MB FETCH killer).
// B=4, T=4096, D=256, K=16, chunk CH=16.

typedef __bf16 bf16x8 __attribute__((ext_vector_type(8)));
typedef float  f32x4  __attribute__((ext_vector_type(4)));
typedef unsigned short u16;
typedef unsigned int   u32;

__device__ static inline u16 f2bf(float f) {          // RNE f32->bf16
    unsigned int u = __float_as_uint(f);
    u = (u + 0x7fffu + ((u >> 16) & 1u)) >> 16;
    return (u16)u;
}

__device__ static inline void gload16(const void* g, void* l) {
    __builtin_amdgcn_global_load_lds((const __attribute__((address_space(1))) void*)g,
                                     (__attribute__((address_space(3))) void*)l, 16, 0, 0);
}

// ---------------- k0: WT[e][d*16+k] = bf16(W[k][e][d]) ----------------
__global__ __launch_bounds__(256) void k0_wt(const float* __restrict__ W, u16* __restrict__ WT) {
    const int e = blockIdx.x, d = threadIdx.x;
    union { u16 u[16]; uint4 v[2]; } ob;
#pragma unroll
    for (int k = 0; k < 16; ++k)
        ob.u[k] = f2bf(W[((size_t)k * 256 + e) * 256 + d]);
    uint4* dst = (uint4*)(WT + (size_t)e * 4096 + d * 16);
    dst[0] = ob.v[0]; dst[1] = ob.v[1];
}

// ------- k1: chunk sums U[b,c,d,k] = sum_{s} phi*x  AND  xT[b][d][t] = x -------
__global__ __launch_bounds__(256) void k1_sums(const float* __restrict__ x,
                                               const float* __restrict__ phi,
                                               float* __restrict__ U,
                                               float* __restrict__ xT) {
    __shared__ float phis[256];
    const int tid = threadIdx.x;
    const int b = blockIdx.x, c = blockIdx.y;
    const int t0 = c * 16;
    phis[tid] = phi[t0 * 16 + tid];
    __syncthreads();
    float acc[16], xr[16];
#pragma unroll
    for (int k = 0; k < 16; ++k) acc[k] = 0.f;
#pragma unroll
    for (int s = 0; s < 16; ++s) {
        xr[s] = x[(size_t)((b << 12) + t0 + s) * 256 + tid];
        union { float f[16]; float4 v[4]; } pv;
#pragma unroll
        for (int j = 0; j < 4; ++j) pv.v[j] = *(const float4*)&phis[s * 16 + j * 4];
#pragma unroll
        for (int k = 0; k < 16; ++k) acc[k] = fmaf(pv.f[k], xr[s], acc[k]);
    }
    float4* Up = (float4*)(U + ((size_t)((b * 256 + c) * 256 + tid)) * 16);
    union { float f[16]; float4 v[4]; } ov;
#pragma unroll
    for (int k = 0; k < 16; ++k) ov.f[k] = acc[k];
#pragma unroll
    for (int j = 0; j < 4; ++j) Up[j] = ov.v[j];
    // transposed copy: xT[b][d=tid][t0..t0+15]  (64B contiguous per thread)
    float4* xtp = (float4*)(xT + ((size_t)(b * 256 + tid)) * 4096 + t0);
#pragma unroll
    for (int j = 0; j < 4; ++j)
        xtp[j] = make_float4(xr[4 * j], xr[4 * j + 1], xr[4 * j + 2], xr[4 * j + 3]);
}

// ---------------- k2: exclusive scan of U over c (in place), coalesced ----------------
__global__ __launch_bounds__(256) void k2_scan(float* __restrict__ U) {
    const int b  = blockIdx.x;                     // grid (4,64)
    const int dl = threadIdx.x & 63;
    const int dk = blockIdx.y * 64 + dl;
    const int q  = threadIdx.x >> 6;               // c-quarter 0..3
    float* base = U + (size_t)b * 1048576 + (size_t)(q * 64) * 4096 + dk;
    float s = 0.f;
#pragma unroll 8
    for (int j = 0; j < 64; ++j) s += base[(size_t)j * 4096];
    __shared__ float qs[4][64];
    qs[q][dl] = s;
    __syncthreads();
    float pre = 0.f;
#pragma unroll
    for (int i = 0; i < 4; ++i) pre += (i < q) ? qs[i][dl] : 0.f;
    float run = pre;
#pragma unroll 8
    for (int j = 0; j < 64; ++j) {
        const float v = base[(size_t)j * 4096];
        base[(size_t)j * 4096] = run;
        run += v;
    }
}

// ---------------- k4: fused A-build + GEMM, m97 geometry, ks-split=4 ----------------
// BM=128, BN=128, BK=64, 16 K-steps. 256 thr = 4 waves, each 64x64
// (acc[4][4]). All threads: 2 kf-pair chains (x from xT: 64B contiguous;
// phi from LDS) + 4 B-stage gload16 + 32 MFMA/step. Single-buffered,
// 2 barriers/step. LDS 40KB: A[16384]@0, B[16384]@16384, phis[8192]@32768.
__global__ __launch_bounds__(256, 3) void k4_fused(const float* __restrict__ xT,
                                                   const float* __restrict__ phi,
                                                   const float* __restrict__ U,
                                                   const u16* __restrict__ BT,
                                                   float* __restrict__ C) {
    __shared__ __align__(16) char smem[40960];
    const int tid = threadIdx.x;
    const int mb = blockIdx.x >> 1, nb = blockIdx.x & 1;
    const int ks = blockIdx.y;                   // kdim quarter 0..3
    const int m0 = mb * 128, n0 = nb * 128;
    const int b  = m0 >> 12, t0 = m0 & 4095, c0 = t0 >> 4;
    const int w = tid >> 6, l = tid & 63;
    const int wm = (w >> 1) * 64, wn = (w & 1) * 64;
    const int lg = l >> 4, lr = l & 15;
    f32x4 acc[4][4] = {};

    // chain mapping: tid = ch*32 + dl*8 + kp  (2 chains: k = 2kp, 2kp+1)
    const int kp = tid & 7, dl = (tid >> 3) & 3, ch = tid >> 5;   // ch 0..7
    const int colb = dl * 32 + kp * 4;
    const char* pb = smem + 32768 + (ch * 16) * 64 + kp * 8;

    // B staging: 4 gload16/thread; row = c*32 + tr
    const int tr = tid >> 3;
    const char* bsrc = (const char*)BT + (size_t)(n0 + tr) * 8192 + ks * 2048
                     + (((tid & 7) * 16) ^ ((tr & 7) << 4));

    auto stageB = [&](int kt) {
        const char* src = bsrc + (size_t)kt * 128;
        char* dst = smem + 16384 + tid * 16;
#pragma unroll
        for (int c = 0; c < 4; ++c)
            gload16(src + (size_t)c * 262144, dst + c * 4096);
    };
    auto chains = [&](int kt) {
        const int d = ks * 64 + kt * 4 + dl;
        const float2 us = *(const float2*)&U[((size_t)((b * 256 + c0 + ch) * 256 + d)) * 16 + kp * 2];
        // xT row d, t-range [t0+ch*16, +16): 64B contiguous, 8-lane broadcast
        const float4* xp = (const float4*)(xT + ((size_t)(b * 256 + d)) * 4096 + t0 + ch * 16);
        float4 xv[4];
#pragma unroll
        for (int q = 0; q < 4; ++q) xv[q] = xp[q];
        float r0 = us.x, r1 = us.y;
        char* Ab = smem + ch * 2048;
#pragma unroll
        for (int q = 0; q < 4; ++q) {
#pragma unroll
            for (int j = 0; j < 4; ++j) {
                const int s = q * 4 + j;
                const float xs = (j == 0) ? xv[q].x : (j == 1) ? xv[q].y
                               : (j == 2) ? xv[q].z : xv[q].w;
                const float2 p = *(const float2*)(pb + s * 64);
                r0 = fmaf(p.x, xs, r0);
                r1 = fmaf(p.y, xs, r1);
                const float v0 = p.x * r0, v1 = p.y * r1;
                u32 pk;
                asm("v_cvt_pk_bf16_f32 %0, %1, %2" : "=v"(pk) : "v"(v0), "v"(v1));
                *(u32*)(Ab + s * 128 + (colb ^ ((s & 7) << 4))) = pk;
            }
        }
    };
    auto mfma_phase = [&]() {
        const char* Abase = smem;
        const char* Bbase = smem + 16384;
#pragma unroll
        for (int kk = 0; kk < 2; ++kk) {
            const int kb = kk * 64 + lg * 16;
            bf16x8 af[4], bfv[4];
#pragma unroll
            for (int mi = 0; mi < 4; ++mi) {
                const int r = wm + mi * 16 + lr;
                af[mi] = *(const bf16x8*)(Abase + r * 128 + (kb ^ ((r & 7) << 4)));
            }
#pragma unroll
            for (int ni = 0; ni < 4; ++ni) {
                const int n = wn + ni * 16 + lr;
                bfv[ni] = *(const bf16x8*)(Bbase + n * 128 + (kb ^ ((n & 7) << 4)));
            }
#pragma unroll
            for (int mi = 0; mi < 4; ++mi)
#pragma unroll
                for (int ni = 0; ni < 4; ++ni)
                    acc[mi][ni] = __builtin_amdgcn_mfma_f32_16x16x32_bf16(
                        af[mi], bfv[ni], acc[mi][ni], 0, 0, 0);
        }
    };

    // prologue: phi tile -> LDS; B(0) in flight; barrier; A(0) chains; barrier
    {
        const float4* psrc = (const float4*)(phi + (size_t)t0 * 16) + tid * 2;
        float4* pdst = (float4*)(smem + 32768) + tid * 2;
        pdst[0] = psrc[0]; pdst[1] = psrc[1];
    }
    stageB(0);
    __syncthreads();                 // phis visible, B(0) landed
    chains(0);
    __syncthreads();                 // A(0) visible

    for (int kt = 0; kt < 16; ++kt) {
        __builtin_amdgcn_s_setprio(1);
        mfma_phase();
        __builtin_amdgcn_s_setprio(0);
        __syncthreads();             // done reading A,B
        if (kt < 15) {
            stageB(kt + 1);
            chains(kt + 1);
            __syncthreads();         // drains vm (B) + lgkm (A writes)
        }
    }

    // epilogue: four contributions per element (ks=0..3), commutative f32 adds
#pragma unroll
    for (int mi = 0; mi < 4; ++mi)
#pragma unroll
        for (int ni = 0; ni < 4; ++ni)
#pragma unroll
            for (int r = 0; r < 4; ++r) {
                const int row = m0 + wm + mi * 16 + lg * 4 + r;
                const int col = n0 + wn + ni * 16 + lr;
                unsafeAtomicAdd(&C[(size_t)row * 256 + col], acc[mi][ni][r]);
            }
}

extern "C" void kernel_launch(void* const* d_in, const int* in_sizes, int n_in,
                              void* d_out, int out_size, void* d_ws, size_t ws_size,
                              hipStream_t stream) {
    const float* x   = (const float*)d_in[0];   // (4,4096,256)
    const float* W   = (const float*)d_in[1];   // (16,256,256)
    const float* phi = (const float*)d_in[2];   // (4096,16)
    float* out = (float*)d_out;                 // (4,4096,256) f32

    char* ws = (char*)d_ws;
    u16*   WT = (u16*)ws;                       // 2 MB
    float* U  = (float*)(ws + (2u << 20));      // 16 MB
    float* xT = (float*)(ws + (18u << 20));     // 16 MB, [b][d][t]

    k0_wt  <<<256, 256, 0, stream>>>(W, WT);
    k1_sums<<<dim3(4, 256), 256, 0, stream>>>(x, phi, U, xT);
    k2_scan<<<dim3(4, 64), 256, 0, stream>>>(U);
    hipMemsetAsync(d_out, 0, (size_t)out_size * sizeof(float), stream);
    k4_fused<<<dim3(256, 4), 256, 0, stream>>>(xT, phi, U, WT, out);
}